// Round 15
// baseline (396.601 us; speedup 1.0000x reference)
//
#include <hip/hip_runtime.h>
#include <math.h>

#define N_USERS 100000
#define N_ITEMS 50000
#define NE      2000000
#define NB      100000
#define H       64
#define BN_EPS  1e-5f
#define P_PART  8                          // node partitions (1 per XCD)
#define U_LOC   (N_USERS / P_PART)         // 12500
#define I_LOC   (N_ITEMS / P_PART)         // 6250
#define HSLOTS  (U_LOC + I_LOC)            // 18750 slots = 75 KB LDS (int)
#define S_SLICES 50
#define NBLK_CSR (P_PART * S_SLICES)       // 400
#define E_SLICE  (NE / S_SLICES)           // 40000 (mult of 4, 16B-aligned)
#define Q_SLICE  (E_SLICE / 4)             // 10000 int4 quads
#define SCAN_CHUNK 2048                    // elems per scan block (256 thr x 8)
#define T_CSR   1024                       // threads per CSR block (32 waves/CU w/ 2 blocks)

typedef __attribute__((ext_vector_type(8))) short bf16x8;
typedef __attribute__((ext_vector_type(4))) float f32x4;
typedef __attribute__((ext_vector_type(4))) int   i32x4;

static __device__ __forceinline__ int rfl(int x) { return __builtin_amdgcn_readfirstlane(x); }

static __device__ __forceinline__ unsigned short f2bf(float f) {   // RTNE
  union { float f; unsigned u; } v; v.f = f;
  const unsigned r = v.u + 0x7fffu + ((v.u >> 16) & 1u);
  return (unsigned short)(r >> 16);
}
static __device__ __forceinline__ float bf2f(unsigned short h) {
  union { unsigned u; float f; } v; v.u = (unsigned)h << 16;
  return v.f;
}
static __device__ __forceinline__ float bfu_lo(unsigned x) {
  union { unsigned u; float f; } v; v.u = x << 16;
  return v.f;
}
static __device__ __forceinline__ float bfu_hi(unsigned x) {
  union { unsigned u; float f; } v; v.u = x & 0xffff0000u;
  return v.f;
}

// ---------------- weight pre-pack into MFMA fragment order ----------------
// blocks 0..7: user proj (K=256); 8..11: item proj (K=128);
// 12..27: conv tables; 28..31: fc1 head (K=128).
__global__ __launch_bounds__(256) void pack_kernel(
    const float* __restrict__ upW, const float* __restrict__ ipW,
    const float* __restrict__ ulW, const float* __restrict__ urW,
    const float* __restrict__ ilW, const float* __restrict__ irW,
    const float* __restrict__ f1W, unsigned short* __restrict__ dst) {
  const int b = blockIdx.x;
  const int ct = threadIdx.x >> 6, lane = threadIdx.x & 63;
  const float* src;
  int krow0;
  if (b < 8)       { src = upW; krow0 = b * 32; }
  else if (b < 12) { src = ipW; krow0 = (b - 8) * 32; }
  else if (b < 28) {
    const int idx = b - 12, t = idx >> 2, ks = idx & 3;
    const int layer = t & 1;
    const float* Wl = (t < 2) ? ulW : ilW;
    const float* Wr = (t < 2) ? urW : irW;
    src = ((ks < 2) ? Wl : Wr) + layer * 4096;
    krow0 = ((ks < 2) ? ks : ks - 2) * 32;
  } else { src = f1W; krow0 = (b - 28) * 32; }
  unsigned short* out = dst + (size_t)b * 2048 + ((size_t)ct * 64 + lane) * 8;
  const int col = ct * 16 + (lane & 15);
  const int kr = krow0 + (lane >> 4) * 8;
#pragma unroll
  for (int j = 0; j < 8; j++) out[j] = f2bf(src[(kr + j) * 64 + col]);
}

// ---------------- proj: Y[N,64] = bf16(X[N,K] @ W + b) via MFMA ----------------
template<int K>
__global__ __launch_bounds__(256) void proj_mfma(
    const float* __restrict__ X, const unsigned short* __restrict__ Wf,
    const float* __restrict__ bias, unsigned short* __restrict__ Y, int nrows) {
  const int lane = threadIdx.x & 63;
  const int wave = rfl((int)(threadIdx.x >> 6));
  const int r0 = (blockIdx.x * 4 + wave) * 16;
  if (r0 >= nrows) return;
  const int arow = r0 + (lane & 15);
  const int ar = arow < nrows ? arow : nrows - 1;
  const int k0 = (lane >> 4) * 8;
  f32x4 acc[4] = {};
#pragma unroll
  for (int ks = 0; ks < K / 32; ks++) {
    const float* xp = X + (size_t)ar * K + ks * 32 + k0;
    const float4 xa = *reinterpret_cast<const float4*>(xp);
    const float4 xb = *reinterpret_cast<const float4*>(xp + 4);
    bf16x8 af;
    af[0] = f2bf(xa.x); af[1] = f2bf(xa.y); af[2] = f2bf(xa.z); af[3] = f2bf(xa.w);
    af[4] = f2bf(xb.x); af[5] = f2bf(xb.y); af[6] = f2bf(xb.z); af[7] = f2bf(xb.w);
#pragma unroll
    for (int ct = 0; ct < 4; ct++) {
      const bf16x8 bfr = *reinterpret_cast<const bf16x8*>(
          Wf + ((size_t)(ks * 4 + ct) * 64 + lane) * 8);
      acc[ct] = __builtin_amdgcn_mfma_f32_16x16x32_bf16(af, bfr, acc[ct], 0, 0, 0);
    }
  }
  const int orow0 = r0 + (lane >> 4) * 4;
#pragma unroll
  for (int ct = 0; ct < 4; ct++) {
    const int col = ct * 16 + (lane & 15);
    const float bv = bias[col];
#pragma unroll
    for (int i = 0; i < 4; i++) {
      const int r = orow0 + i;
      if (r < nrows) Y[(size_t)r * 64 + col] = f2bf(acc[ct][i] + bv);
    }
  }
}

// ---------------- conv: Y = bf16(relu(BN([AGG|XS] @ [Wl;Wr] + bl))) ----------------
__global__ __launch_bounds__(256) void conv_mfma(
    const unsigned short* __restrict__ AGG, const unsigned short* __restrict__ XS,
    const unsigned short* __restrict__ Wf, const float* __restrict__ bl,
    const float* __restrict__ gm, const float* __restrict__ bt,
    const float* __restrict__ mu, const float* __restrict__ vr,
    unsigned short* __restrict__ Y, int nrows) {
  const int lane = threadIdx.x & 63;
  const int wave = rfl((int)(threadIdx.x >> 6));
  const int r0 = (blockIdx.x * 4 + wave) * 16;
  if (r0 >= nrows) return;
  const int arow = r0 + (lane & 15);
  const int ar = arow < nrows ? arow : nrows - 1;
  const int k0 = (lane >> 4) * 8;
  f32x4 acc[4] = {};
#pragma unroll
  for (int ks = 0; ks < 4; ks++) {
    const unsigned short* ap =
        (ks < 2 ? AGG : XS) + (size_t)ar * 64 + (ks & 1) * 32 + k0;
    const bf16x8 af = *reinterpret_cast<const bf16x8*>(ap);
#pragma unroll
    for (int ct = 0; ct < 4; ct++) {
      const bf16x8 bfr = *reinterpret_cast<const bf16x8*>(
          Wf + ((size_t)(ks * 4 + ct) * 64 + lane) * 8);
      acc[ct] = __builtin_amdgcn_mfma_f32_16x16x32_bf16(af, bfr, acc[ct], 0, 0, 0);
    }
  }
  const int orow0 = r0 + (lane >> 4) * 4;
#pragma unroll
  for (int ct = 0; ct < 4; ct++) {
    const int col = ct * 16 + (lane & 15);
    const float s = gm[col] * rsqrtf(vr[col] + BN_EPS);
    const float C = (bl[col] - mu[col]) * s + bt[col];
#pragma unroll
    for (int i = 0; i < 4; i++) {
      const int r = orow0 + i;
      if (r < nrows)
        Y[(size_t)r * 64 + col] = f2bf(fmaxf(fmaf(acc[ct][i], s, C), 0.f));
    }
  }
}

// ---------------- CSR build: P=8 (1/XCD), 1024-thread blocks, NT edge loads --
// NT loads stop the 8x-replicated edge stream from evicting dirty adjacency/
// histogram lines in the owning XCD's L2 (kills write amplification, R10);
// T=1024 raises occupancy to 32 waves/CU (2 blocks x 16 waves) so the NT
// L3-latency is hidden (R10's failure was at 28% occ; R13 showed waves alone
// don't help -- the PAIR is the theory).
__global__ __launch_bounds__(T_CSR) void hist2_kernel(
    const int* __restrict__ src, const int* __restrict__ dst,
    unsigned short* __restrict__ PH) {
  __shared__ int h[HSLOTS];
  const int p = blockIdx.x & (P_PART - 1);
  const int s = blockIdx.x >> 3;
  for (int i = threadIdx.x; i < HSLOTS; i += T_CSR) h[i] = 0;
  __syncthreads();
  const int uLo = p * U_LOC, iLo = p * I_LOC;
  const int e0 = s * E_SLICE;
  const i32x4* s4 = reinterpret_cast<const i32x4*>(src + e0);
  const i32x4* d4 = reinterpret_cast<const i32x4*>(dst + e0);
  for (int i = threadIdx.x; i < Q_SLICE; i += T_CSR) {
    const i32x4 us = __builtin_nontemporal_load(&s4[i]);
    const i32x4 ds = __builtin_nontemporal_load(&d4[i]);
#pragma unroll
    for (int q = 0; q < 4; q++) {
      const int ul = us[q] - uLo;
      if ((unsigned)ul < (unsigned)U_LOC) atomicAdd(&h[ul], 1);
      const int il = ds[q] - iLo;
      if ((unsigned)il < (unsigned)I_LOC) atomicAdd(&h[U_LOC + il], 1);
    }
  }
  __syncthreads();
  unsigned short* out = PH + (size_t)blockIdx.x * HSLOTS;
  for (int i = threadIdx.x; i < HSLOTS; i += T_CSR)
    __builtin_nontemporal_store((unsigned short)h[i], &out[i]);
}

__global__ __launch_bounds__(256) void combine_kernel(
    unsigned short* __restrict__ PH, int* __restrict__ cntU,
    int* __restrict__ cntI) {
  const int g = blockIdx.x * 256 + threadIdx.x;
  if (g >= P_PART * HSLOTS) return;
  const int x = g / HSLOTS;
  const int n = g - x * HSLOTS;
  unsigned short* p = PH + (size_t)x * HSLOTS + n;
  int run = 0;
#pragma unroll 2
  for (int s = 0; s < S_SLICES; s++) {
    unsigned short* q = p + (size_t)s * (P_PART * HSLOTS);
    const int v = (int)__builtin_nontemporal_load(q);
    __builtin_nontemporal_store((unsigned short)run, q);
    run += v;
  }
  if (n < U_LOC) cntU[x * U_LOC + n] = run;
  else           cntI[x * I_LOC + (n - U_LOC)] = run;
}

// ---------------- two-level parallel exclusive scan ----------------
__global__ __launch_bounds__(256) void scan1_kernel(
    const int* __restrict__ cnt, int* __restrict__ row,
    int* __restrict__ bsum, int n) {
  __shared__ int wtot[4];
  const int tid = threadIdx.x;
  const int lane = tid & 63, wv = tid >> 6;
  const int i0 = blockIdx.x * SCAN_CHUNK + tid * 8;
  int sacc[8];
  int run = 0;
#pragma unroll
  for (int k = 0; k < 8; k++) {
    const int v = (i0 + k < n) ? cnt[i0 + k] : 0;
    run += v;
    sacc[k] = run;
  }
  int x = run;
#pragma unroll
  for (int off = 1; off < 64; off <<= 1) {
    const int y = __shfl_up(x, off);
    if (lane >= off) x += y;
  }
  if (lane == 63) wtot[wv] = x;
  __syncthreads();
  int woff = 0;
#pragma unroll
  for (int k = 0; k < 4; k++) woff += (k < wv) ? wtot[k] : 0;
  const int excl = (x - run) + woff;
#pragma unroll
  for (int k = 0; k < 8; k++)
    if (i0 + k < n) row[i0 + k + 1] = excl + sacc[k];
  if (tid == 255) bsum[blockIdx.x] = excl + run;
}

__global__ __launch_bounds__(256) void scan3_kernel(
    const int* __restrict__ bsum, int* __restrict__ row, int n) {
  __shared__ int off_s;
  const int b = blockIdx.x;
  const int tid = threadIdx.x;
  if (tid < 64) {
    int v = (tid < b) ? bsum[tid] : 0;
#pragma unroll
    for (int off = 32; off; off >>= 1) v += __shfl_xor(v, off);
    if (tid == 0) off_s = v;
  }
  __syncthreads();
  const int off = off_s;
  if (b == 0) {
    if (tid == 0) row[0] = 0;
    return;
  }
  const int i0 = b * SCAN_CHUNK + tid * 8;
#pragma unroll
  for (int k = 0; k < 8; k++)
    if (i0 + k < n) row[i0 + k + 1] += off;
}

__global__ __launch_bounds__(T_CSR) void scatter2_kernel(
    const int* __restrict__ src, const int* __restrict__ dst,
    const unsigned short* __restrict__ PH, const int* __restrict__ rowU,
    const int* __restrict__ rowI, int* __restrict__ adjU,
    int* __restrict__ adjI) {
  __shared__ int pos[HSLOTS];
  const int p = blockIdx.x & (P_PART - 1);
  const int s = blockIdx.x >> 3;
  const int uLo = p * U_LOC, iLo = p * I_LOC;
  const unsigned short* pre = PH + (size_t)blockIdx.x * HSLOTS;
  for (int i = threadIdx.x; i < U_LOC; i += T_CSR)
    pos[i] = rowU[uLo + i] + (int)__builtin_nontemporal_load(&pre[i]);
  for (int i = threadIdx.x; i < I_LOC; i += T_CSR)
    pos[U_LOC + i] = rowI[iLo + i] + (int)__builtin_nontemporal_load(&pre[U_LOC + i]);
  __syncthreads();
  const int e0 = s * E_SLICE;
  const i32x4* s4 = reinterpret_cast<const i32x4*>(src + e0);
  const i32x4* d4 = reinterpret_cast<const i32x4*>(dst + e0);
  for (int i = threadIdx.x; i < Q_SLICE; i += T_CSR) {
    const i32x4 us = __builtin_nontemporal_load(&s4[i]);
    const i32x4 ds = __builtin_nontemporal_load(&d4[i]);
#pragma unroll
    for (int q = 0; q < 4; q++) {
      const int u = us[q], it = ds[q];
      const int ul = u - uLo, il = it - iLo;
      if ((unsigned)ul < (unsigned)U_LOC) {
        const int pp = atomicAdd(&pos[ul], 1);
        adjU[pp] = it;
      }
      if ((unsigned)il < (unsigned)I_LOC) {
        const int pp = atomicAdd(&pos[U_LOC + il], 1);
        adjI[pp] = u;
      }
    }
  }
}

// ---------------- aggregations: 4 neighbor rows per wave instruction ----------
__global__ __launch_bounds__(256) void agg_max_kernel(
    const unsigned short* __restrict__ feat, const int* __restrict__ rowptr,
    const int* __restrict__ adj, unsigned short* __restrict__ out, int nseg) {
  const int lane = threadIdx.x & 63;
  const int wid  = rfl((int)(threadIdx.x >> 6));
  const int g    = lane >> 4;
  const int c4   = (lane & 15) * 4;
  for (int s = blockIdx.x * 4 + wid; s < nseg; s += gridDim.x * 4) {
    const int beg = rowptr[s], end = rowptr[s + 1];
    float m0 = -INFINITY, m1 = -INFINITY, m2 = -INFINITY, m3 = -INFINITY;
    float n0 = -INFINITY, n1 = -INFINITY, n2 = -INFINITY, n3 = -INFINITY;
    int j = beg;
    for (; j + 8 <= end; j += 8) {
      const int ia = adj[j + g];
      const int ib = adj[j + 4 + g];
      const uint2 va = *reinterpret_cast<const uint2*>(feat + (size_t)ia * H + c4);
      const uint2 vb = *reinterpret_cast<const uint2*>(feat + (size_t)ib * H + c4);
      m0 = fmaxf(m0, bfu_lo(va.x)); m1 = fmaxf(m1, bfu_hi(va.x));
      m2 = fmaxf(m2, bfu_lo(va.y)); m3 = fmaxf(m3, bfu_hi(va.y));
      n0 = fmaxf(n0, bfu_lo(vb.x)); n1 = fmaxf(n1, bfu_hi(vb.x));
      n2 = fmaxf(n2, bfu_lo(vb.y)); n3 = fmaxf(n3, bfu_hi(vb.y));
    }
    for (; j < end; j += 4) {
      if (j + g < end) {
        const int ia = adj[j + g];
        const uint2 va = *reinterpret_cast<const uint2*>(feat + (size_t)ia * H + c4);
        m0 = fmaxf(m0, bfu_lo(va.x)); m1 = fmaxf(m1, bfu_hi(va.x));
        m2 = fmaxf(m2, bfu_lo(va.y)); m3 = fmaxf(m3, bfu_hi(va.y));
      }
    }
    m0 = fmaxf(m0, n0); m1 = fmaxf(m1, n1);
    m2 = fmaxf(m2, n2); m3 = fmaxf(m3, n3);
    m0 = fmaxf(m0, __shfl_xor(m0, 16)); m0 = fmaxf(m0, __shfl_xor(m0, 32));
    m1 = fmaxf(m1, __shfl_xor(m1, 16)); m1 = fmaxf(m1, __shfl_xor(m1, 32));
    m2 = fmaxf(m2, __shfl_xor(m2, 16)); m2 = fmaxf(m2, __shfl_xor(m2, 32));
    m3 = fmaxf(m3, __shfl_xor(m3, 16)); m3 = fmaxf(m3, __shfl_xor(m3, 32));
    if (lane < 16) {
      uint2 o;
      if (end > beg) {
        o.x = (unsigned)f2bf(m0) | ((unsigned)f2bf(m1) << 16);
        o.y = (unsigned)f2bf(m2) | ((unsigned)f2bf(m3) << 16);
      } else {
        o.x = 0; o.y = 0;   // empty segment -> 0 (PyG)
      }
      *reinterpret_cast<uint2*>(out + (size_t)s * H + c4) = o;
    }
  }
}

__global__ __launch_bounds__(256) void agg_mean_kernel(
    const unsigned short* __restrict__ feat, const int* __restrict__ rowptr,
    const int* __restrict__ adj, unsigned short* __restrict__ out, int nseg) {
  const int lane = threadIdx.x & 63;
  const int wid  = rfl((int)(threadIdx.x >> 6));
  const int g    = lane >> 4;
  const int c4   = (lane & 15) * 4;
  for (int s = blockIdx.x * 4 + wid; s < nseg; s += gridDim.x * 4) {
    const int beg = rowptr[s], end = rowptr[s + 1];
    float a0 = 0.f, a1 = 0.f, a2 = 0.f, a3 = 0.f;
    float b0 = 0.f, b1 = 0.f, b2 = 0.f, b3 = 0.f;
    int j = beg;
    for (; j + 8 <= end; j += 8) {
      const int ia = adj[j + g];
      const int ib = adj[j + 4 + g];
      const uint2 va = *reinterpret_cast<const uint2*>(feat + (size_t)ia * H + c4);
      const uint2 vb = *reinterpret_cast<const uint2*>(feat + (size_t)ib * H + c4);
      a0 += bfu_lo(va.x); a1 += bfu_hi(va.x);
      a2 += bfu_lo(va.y); a3 += bfu_hi(va.y);
      b0 += bfu_lo(vb.x); b1 += bfu_hi(vb.x);
      b2 += bfu_lo(vb.y); b3 += bfu_hi(vb.y);
    }
    for (; j < end; j += 4) {
      if (j + g < end) {
        const int ia = adj[j + g];
        const uint2 va = *reinterpret_cast<const uint2*>(feat + (size_t)ia * H + c4);
        a0 += bfu_lo(va.x); a1 += bfu_hi(va.x);
        a2 += bfu_lo(va.y); a3 += bfu_hi(va.y);
      }
    }
    a0 += b0; a1 += b1; a2 += b2; a3 += b3;
    a0 += __shfl_xor(a0, 16); a0 += __shfl_xor(a0, 32);
    a1 += __shfl_xor(a1, 16); a1 += __shfl_xor(a1, 32);
    a2 += __shfl_xor(a2, 16); a2 += __shfl_xor(a2, 32);
    a3 += __shfl_xor(a3, 16); a3 += __shfl_xor(a3, 32);
    if (lane < 16) {
      const float inv = 1.f / (float)((end - beg) > 1 ? (end - beg) : 1);
      uint2 o;
      o.x = (unsigned)f2bf(a0 * inv) | ((unsigned)f2bf(a1 * inv) << 16);
      o.y = (unsigned)f2bf(a2 * inv) | ((unsigned)f2bf(a3 * inv) << 16);
      *reinterpret_cast<uint2*>(out + (size_t)s * H + c4) = o;
    }
  }
}

// ---------------- head via MFMA: 16 edges/wave ----------------
__global__ __launch_bounds__(256) void head_mfma(
    const unsigned short* __restrict__ ux, const unsigned short* __restrict__ ix,
    const int* __restrict__ eliU, const int* __restrict__ eliI,
    const unsigned short* __restrict__ W1f, const float* __restrict__ b1,
    const float* __restrict__ W2, const float* __restrict__ b2,
    float* __restrict__ out) {
  const int lane = threadIdx.x & 63;
  const int wave = rfl((int)(threadIdx.x >> 6));
  const int r0 = (blockIdx.x * 4 + wave) * 16;
  if (r0 >= NB) return;
  const int rr = r0 + (lane & 15);
  const int rc = rr < NB ? rr : NB - 1;
  const int idxU = eliU[rc], idxI = eliI[rc];
  const int k0 = (lane >> 4) * 8;
  f32x4 acc[4] = {};
#pragma unroll
  for (int ks = 0; ks < 4; ks++) {
    const unsigned short* ap = (ks < 2)
        ? ux + (size_t)idxU * 64 + (ks & 1) * 32 + k0
        : ix + (size_t)idxI * 64 + (ks & 1) * 32 + k0;
    const bf16x8 af = *reinterpret_cast<const bf16x8*>(ap);
#pragma unroll
    for (int ct = 0; ct < 4; ct++) {
      const bf16x8 bfr = *reinterpret_cast<const bf16x8*>(
          W1f + ((size_t)(ks * 4 + ct) * 64 + lane) * 8);
      acc[ct] = __builtin_amdgcn_mfma_f32_16x16x32_bf16(af, bfr, acc[ct], 0, 0, 0);
    }
  }
  float p[4][4];
#pragma unroll
  for (int i = 0; i < 4; i++)
#pragma unroll
    for (int o = 0; o < 4; o++) p[i][o] = 0.f;
#pragma unroll
  for (int ct = 0; ct < 4; ct++) {
    const int col = ct * 16 + (lane & 15);
    const float bb = b1[col];
    const float wa = W2[col * 4 + 0], wb = W2[col * 4 + 1];
    const float wc = W2[col * 4 + 2], wd = W2[col * 4 + 3];
#pragma unroll
    for (int i = 0; i < 4; i++) {
      const float h = fmaxf(acc[ct][i] + bb, 0.f);
      p[i][0] = fmaf(h, wa, p[i][0]);
      p[i][1] = fmaf(h, wb, p[i][1]);
      p[i][2] = fmaf(h, wc, p[i][2]);
      p[i][3] = fmaf(h, wd, p[i][3]);
    }
  }
#pragma unroll
  for (int off = 1; off < 16; off <<= 1) {
#pragma unroll
    for (int i = 0; i < 4; i++) {
      p[i][0] += __shfl_xor(p[i][0], off);
      p[i][1] += __shfl_xor(p[i][1], off);
      p[i][2] += __shfl_xor(p[i][2], off);
      p[i][3] += __shfl_xor(p[i][3], off);
    }
  }
  if ((lane & 15) == 0) {
    const int row0 = r0 + (lane >> 4) * 4;
#pragma unroll
    for (int i = 0; i < 4; i++) {
      const int r = row0 + i;
      if (r < NB) {
        float4 o4 = { p[i][0] + b2[0], p[i][1] + b2[1],
                      p[i][2] + b2[2], p[i][3] + b2[3] };
        *reinterpret_cast<float4*>(out + (size_t)r * 4) = o4;
      }
    }
  }
}

// ---------------- launch ----------------
extern "C" void kernel_launch(void* const* d_in, const int* in_sizes, int n_in,
                              void* d_out, int out_size, void* d_ws, size_t ws_size,
                              hipStream_t stream) {
  const float* userF = (const float*)d_in[0];
  const float* itemF = (const float*)d_in[1];
  const int*   src   = (const int*)d_in[2];
  const int*   dst   = src + NE;
  const int*   eliU  = (const int*)d_in[3];
  const int*   eliI  = eliU + NB;
  const float* upW = (const float*)d_in[4],  *upb = (const float*)d_in[5];
  const float* ipW = (const float*)d_in[6],  *ipb = (const float*)d_in[7];
  const float* ulW = (const float*)d_in[8],  *ulb = (const float*)d_in[9];
  const float* urW = (const float*)d_in[10];
  const float* ilW = (const float*)d_in[11], *ilb = (const float*)d_in[12];
  const float* irW = (const float*)d_in[13];
  const float* ug  = (const float*)d_in[14], *ube = (const float*)d_in[15];
  const float* um  = (const float*)d_in[16], *uv  = (const float*)d_in[17];
  const float* ig  = (const float*)d_in[18], *ibe = (const float*)d_in[19];
  const float* im  = (const float*)d_in[20], *iv  = (const float*)d_in[21];
  const float* f1W = (const float*)d_in[22], *f1b = (const float*)d_in[23];
  const float* f2W = (const float*)d_in[24], *f2b = (const float*)d_in[25];
  float* outp = (float*)d_out;

  char* p = (char*)d_ws;
  auto alloc = [&](size_t bytes) {
    char* r = p;
    p += (bytes + 255) & ~(size_t)255;
    return r;
  };
  unsigned short* ux0 = (unsigned short*)alloc((size_t)N_USERS * H * 2);
  unsigned short* ix0 = (unsigned short*)alloc((size_t)N_ITEMS * H * 2);
  char* grp = alloc((size_t)38400 * 1024);
  unsigned short* agU = (unsigned short*)grp;
  unsigned short* agI = agU + (size_t)N_USERS * H;
  unsigned short* ux1 = agI + (size_t)N_ITEMS * H;
  unsigned short* ix1 = ux1 + (size_t)N_USERS * H;
  unsigned short* PH = (unsigned short*)grp;  // 400 x 18750 u16 = 15 MB
  int*   rowU = (int*)alloc((size_t)(N_USERS + 1) * 4);
  int*   rowI = (int*)alloc((size_t)(N_ITEMS + 1) * 4);
  int*   cntU = (int*)alloc((size_t)N_USERS * 4);
  int*   cntI = (int*)alloc((size_t)N_ITEMS * 4);
  int*   adjU = (int*)alloc((size_t)NE * 4);
  int*   adjI = (int*)alloc((size_t)NE * 4);
  int*   bsumU = (int*)alloc(64 * 4);
  int*   bsumI = (int*)alloc(64 * 4);
  unsigned short* wpack = (unsigned short*)alloc((size_t)32 * 2048 * 2);  // 256 KB

  const int G = 2048, T = 256;
  const int SBU = (N_USERS + SCAN_CHUNK - 1) / SCAN_CHUNK;  // 49
  const int SBI = (N_ITEMS + SCAN_CHUNK - 1) / SCAN_CHUNK;  // 25
  pack_kernel<<<32, T, 0, stream>>>(upW, ipW, ulW, urW, ilW, irW, f1W, wpack);
  proj_mfma<256><<<(N_USERS + 63) / 64, T, 0, stream>>>(userF, wpack, upb, ux0, N_USERS);
  proj_mfma<128><<<(N_ITEMS + 63) / 64, T, 0, stream>>>(itemF, wpack + 8 * 2048, ipb, ix0, N_ITEMS);
  hist2_kernel<<<NBLK_CSR, T_CSR, 0, stream>>>(src, dst, PH);
  combine_kernel<<<(P_PART * HSLOTS + 255) / 256, T, 0, stream>>>(PH, cntU, cntI);
  scan1_kernel<<<SBU, T, 0, stream>>>(cntU, rowU, bsumU, N_USERS);
  scan1_kernel<<<SBI, T, 0, stream>>>(cntI, rowI, bsumI, N_ITEMS);
  scan3_kernel<<<SBU, T, 0, stream>>>(bsumU, rowU, N_USERS);
  scan3_kernel<<<SBI, T, 0, stream>>>(bsumI, rowI, N_ITEMS);
  scatter2_kernel<<<NBLK_CSR, T_CSR, 0, stream>>>(src, dst, PH, rowU, rowI, adjU, adjI);

  const unsigned short* uin = ux0;
  const unsigned short* iin = ix0;
  unsigned short* uout = ux1;
  unsigned short* iout = ix1;
  const int GU = (N_USERS + 63) / 64, GI = (N_ITEMS + 63) / 64;
  for (int l = 0; l < 2; l++) {
    unsigned short* cwU = wpack + (12 + 4 * (0 + l)) * 2048;
    unsigned short* cwI = wpack + (12 + 4 * (2 + l)) * 2048;
    agg_max_kernel<<<G, T, 0, stream>>>(iin, rowU, adjU, agU, N_USERS);
    conv_mfma<<<GU, T, 0, stream>>>(agU, uin, cwU, ulb + l * 64,
                                    ug + l * 64, ube + l * 64,
                                    um + l * 64, uv + l * 64, uout, N_USERS);
    agg_mean_kernel<<<G, T, 0, stream>>>(uin, rowI, adjI, agI, N_ITEMS);
    conv_mfma<<<GI, T, 0, stream>>>(agI, iin, cwI, ilb + l * 64,
                                    ig + l * 64, ibe + l * 64,
                                    im + l * 64, iv + l * 64, iout, N_ITEMS);
    const unsigned short* t;
    t = uin; uin = uout; uout = (unsigned short*)t;
    t = iin; iin = iout; iout = (unsigned short*)t;
  }
  head_mfma<<<(NB / 16 + 3) / 4, T, 0, stream>>>(uin, iin, eliU, eliI,
                                                 wpack + 28 * 2048, f1b, f2W, f2b, outp);
}

// Round 16
// 368.072 us; speedup vs baseline: 1.0775x; 1.0775x over previous
//
#include <hip/hip_runtime.h>
#include <math.h>

#define N_USERS 100000
#define N_ITEMS 50000
#define NE      2000000
#define NB      100000
#define H       64
#define BN_EPS  1e-5f
#define P_PART  8                          // node partitions (1 per XCD)
#define U_LOC   (N_USERS / P_PART)         // 12500
#define I_LOC   (N_ITEMS / P_PART)         // 6250
#define HSLOTS  (U_LOC + I_LOC)            // 18750 slots = 75 KB LDS (int)
#define S_SLICES 50
#define NBLK_CSR (P_PART * S_SLICES)       // 400
#define E_SLICE  (NE / S_SLICES)           // 40000 (mult of 4, 16B-aligned)
#define Q_SLICE  (E_SLICE / 4)             // 10000 int4 quads
#define SCAN_CHUNK 2048                    // elems per scan block (256 thr x 8)
#define T_CSR   512                        // threads per CSR block (R13 best)
#define GU_BLK  ((N_USERS + 127) / 128)    // 782 proj-u blocks (8 waves x 16 rows)
#define GI_BLK  ((N_ITEMS + 127) / 128)    // 391 proj-i blocks

typedef __attribute__((ext_vector_type(8))) short bf16x8;
typedef __attribute__((ext_vector_type(4))) float f32x4;
typedef __attribute__((ext_vector_type(4))) int   i32x4;

static __device__ __forceinline__ int rfl(int x) { return __builtin_amdgcn_readfirstlane(x); }

static __device__ __forceinline__ unsigned short f2bf(float f) {   // RTNE
  union { float f; unsigned u; } v; v.f = f;
  const unsigned r = v.u + 0x7fffu + ((v.u >> 16) & 1u);
  return (unsigned short)(r >> 16);
}
static __device__ __forceinline__ float bf2f(unsigned short h) {
  union { unsigned u; float f; } v; v.u = (unsigned)h << 16;
  return v.f;
}
static __device__ __forceinline__ float bfu_lo(unsigned x) {
  union { unsigned u; float f; } v; v.u = x << 16;
  return v.f;
}
static __device__ __forceinline__ float bfu_hi(unsigned x) {
  union { unsigned u; float f; } v; v.u = x & 0xffff0000u;
  return v.f;
}

// ---------------- weight pre-pack into MFMA fragment order ----------------
// blocks 0..7: user proj (K=256); 8..11: item proj (K=128);
// 12..27: conv tables; 28..31: fc1 head (K=128).
__global__ __launch_bounds__(256) void pack_kernel(
    const float* __restrict__ upW, const float* __restrict__ ipW,
    const float* __restrict__ ulW, const float* __restrict__ urW,
    const float* __restrict__ ilW, const float* __restrict__ irW,
    const float* __restrict__ f1W, unsigned short* __restrict__ dst) {
  const int b = blockIdx.x;
  const int ct = threadIdx.x >> 6, lane = threadIdx.x & 63;
  const float* src;
  int krow0;
  if (b < 8)       { src = upW; krow0 = b * 32; }
  else if (b < 12) { src = ipW; krow0 = (b - 8) * 32; }
  else if (b < 28) {
    const int idx = b - 12, t = idx >> 2, ks = idx & 3;
    const int layer = t & 1;
    const float* Wl = (t < 2) ? ulW : ilW;
    const float* Wr = (t < 2) ? urW : irW;
    src = ((ks < 2) ? Wl : Wr) + layer * 4096;
    krow0 = ((ks < 2) ? ks : ks - 2) * 32;
  } else { src = f1W; krow0 = (b - 28) * 32; }
  unsigned short* out = dst + (size_t)b * 2048 + ((size_t)ct * 64 + lane) * 8;
  const int col = ct * 16 + (lane & 15);
  const int kr = krow0 + (lane >> 4) * 8;
#pragma unroll
  for (int j = 0; j < 8; j++) out[j] = f2bf(src[(kr + j) * 64 + col]);
}

// ---------------- proj body (device): one wave = one 16x64 tile ----------------
template<int K>
static __device__ __forceinline__ void proj_body(
    const float* __restrict__ X, const unsigned short* __restrict__ Wf,
    const float* __restrict__ bias, unsigned short* __restrict__ Y,
    int nrows, int bp) {
  const int lane = threadIdx.x & 63;
  const int wave = rfl((int)(threadIdx.x >> 6));     // 0..7
  const int r0 = (bp * 8 + wave) * 16;
  if (r0 >= nrows) return;
  const int arow = r0 + (lane & 15);
  const int ar = arow < nrows ? arow : nrows - 1;
  const int k0 = (lane >> 4) * 8;
  f32x4 acc[4] = {};
#pragma unroll
  for (int ks = 0; ks < K / 32; ks++) {
    const float* xp = X + (size_t)ar * K + ks * 32 + k0;
    const float4 xa = *reinterpret_cast<const float4*>(xp);
    const float4 xb = *reinterpret_cast<const float4*>(xp + 4);
    bf16x8 af;
    af[0] = f2bf(xa.x); af[1] = f2bf(xa.y); af[2] = f2bf(xa.z); af[3] = f2bf(xa.w);
    af[4] = f2bf(xb.x); af[5] = f2bf(xb.y); af[6] = f2bf(xb.z); af[7] = f2bf(xb.w);
#pragma unroll
    for (int ct = 0; ct < 4; ct++) {
      const bf16x8 bfr = *reinterpret_cast<const bf16x8*>(
          Wf + ((size_t)(ks * 4 + ct) * 64 + lane) * 8);
      acc[ct] = __builtin_amdgcn_mfma_f32_16x16x32_bf16(af, bfr, acc[ct], 0, 0, 0);
    }
  }
  const int orow0 = r0 + (lane >> 4) * 4;
#pragma unroll
  for (int ct = 0; ct < 4; ct++) {
    const int col = ct * 16 + (lane & 15);
    const float bv = bias[col];
#pragma unroll
    for (int i = 0; i < 4; i++) {
      const int r = orow0 + i;
      if (r < nrows) Y[(size_t)r * 64 + col] = f2bf(acc[ct][i] + bv);
    }
  }
}

// ---------------- FUSED hist + proj: block-role split ----------------
// Blocks 0..399: histogram (R13's hist2, cached edge loads). Blocks 400+:
// proj_u then proj_i (8 waves x 16 rows each). hist is block-slot-limited to
// ~200 CUs (2/CU at 75KB LDS); proj backfills the rest -> overlap of the
// HBM-stream (proj) and LDS-atomic/L3 (hist) phases in one dispatch.
__global__ __launch_bounds__(T_CSR) void fused_hist_proj(
    const int* __restrict__ src, const int* __restrict__ dst,
    unsigned short* __restrict__ PH,
    const float* __restrict__ userF, const float* __restrict__ itemF,
    const unsigned short* __restrict__ wpack,
    const float* __restrict__ upb, const float* __restrict__ ipb,
    unsigned short* __restrict__ ux0, unsigned short* __restrict__ ix0) {
  __shared__ int h[HSLOTS];
  const int b = blockIdx.x;
  if (b < NBLK_CSR) {
    const int p = b & (P_PART - 1);
    const int s = b >> 3;
    for (int i = threadIdx.x; i < HSLOTS; i += T_CSR) h[i] = 0;
    __syncthreads();
    const int uLo = p * U_LOC, iLo = p * I_LOC;
    const int e0 = s * E_SLICE;
    const i32x4* s4 = reinterpret_cast<const i32x4*>(src + e0);
    const i32x4* d4 = reinterpret_cast<const i32x4*>(dst + e0);
    for (int i = threadIdx.x; i < Q_SLICE; i += T_CSR) {
      const i32x4 us = s4[i];
      const i32x4 ds = d4[i];
#pragma unroll
      for (int q = 0; q < 4; q++) {
        const int ul = us[q] - uLo;
        if ((unsigned)ul < (unsigned)U_LOC) atomicAdd(&h[ul], 1);
        const int il = ds[q] - iLo;
        if ((unsigned)il < (unsigned)I_LOC) atomicAdd(&h[U_LOC + il], 1);
      }
    }
    __syncthreads();
    unsigned short* out = PH + (size_t)b * HSLOTS;
    for (int i = threadIdx.x; i < HSLOTS; i += T_CSR)
      __builtin_nontemporal_store((unsigned short)h[i], &out[i]);
  } else if (b < NBLK_CSR + GU_BLK) {
    proj_body<256>(userF, wpack, upb, ux0, N_USERS, b - NBLK_CSR);
  } else {
    proj_body<128>(itemF, wpack + 8 * 2048, ipb, ix0, N_ITEMS,
                   b - NBLK_CSR - GU_BLK);
  }
}

// ---------------- conv: Y = bf16(relu(BN([AGG|XS] @ [Wl;Wr] + bl))) ----------------
__global__ __launch_bounds__(256) void conv_mfma(
    const unsigned short* __restrict__ AGG, const unsigned short* __restrict__ XS,
    const unsigned short* __restrict__ Wf, const float* __restrict__ bl,
    const float* __restrict__ gm, const float* __restrict__ bt,
    const float* __restrict__ mu, const float* __restrict__ vr,
    unsigned short* __restrict__ Y, int nrows) {
  const int lane = threadIdx.x & 63;
  const int wave = rfl((int)(threadIdx.x >> 6));
  const int r0 = (blockIdx.x * 4 + wave) * 16;
  if (r0 >= nrows) return;
  const int arow = r0 + (lane & 15);
  const int ar = arow < nrows ? arow : nrows - 1;
  const int k0 = (lane >> 4) * 8;
  f32x4 acc[4] = {};
#pragma unroll
  for (int ks = 0; ks < 4; ks++) {
    const unsigned short* ap =
        (ks < 2 ? AGG : XS) + (size_t)ar * 64 + (ks & 1) * 32 + k0;
    const bf16x8 af = *reinterpret_cast<const bf16x8*>(ap);
#pragma unroll
    for (int ct = 0; ct < 4; ct++) {
      const bf16x8 bfr = *reinterpret_cast<const bf16x8*>(
          Wf + ((size_t)(ks * 4 + ct) * 64 + lane) * 8);
      acc[ct] = __builtin_amdgcn_mfma_f32_16x16x32_bf16(af, bfr, acc[ct], 0, 0, 0);
    }
  }
  const int orow0 = r0 + (lane >> 4) * 4;
#pragma unroll
  for (int ct = 0; ct < 4; ct++) {
    const int col = ct * 16 + (lane & 15);
    const float s = gm[col] * rsqrtf(vr[col] + BN_EPS);
    const float C = (bl[col] - mu[col]) * s + bt[col];
#pragma unroll
    for (int i = 0; i < 4; i++) {
      const int r = orow0 + i;
      if (r < nrows)
        Y[(size_t)r * 64 + col] = f2bf(fmaxf(fmaf(acc[ct][i], s, C), 0.f));
    }
  }
}

__global__ __launch_bounds__(256) void combine_kernel(
    unsigned short* __restrict__ PH, int* __restrict__ cntU,
    int* __restrict__ cntI) {
  const int g = blockIdx.x * 256 + threadIdx.x;
  if (g >= P_PART * HSLOTS) return;
  const int x = g / HSLOTS;
  const int n = g - x * HSLOTS;
  unsigned short* p = PH + (size_t)x * HSLOTS + n;
  int run = 0;
#pragma unroll 2
  for (int s = 0; s < S_SLICES; s++) {
    unsigned short* q = p + (size_t)s * (P_PART * HSLOTS);
    const int v = (int)__builtin_nontemporal_load(q);
    __builtin_nontemporal_store((unsigned short)run, q);
    run += v;
  }
  if (n < U_LOC) cntU[x * U_LOC + n] = run;
  else           cntI[x * I_LOC + (n - U_LOC)] = run;
}

// ---------------- two-level parallel exclusive scan ----------------
__global__ __launch_bounds__(256) void scan1_kernel(
    const int* __restrict__ cnt, int* __restrict__ row,
    int* __restrict__ bsum, int n) {
  __shared__ int wtot[4];
  const int tid = threadIdx.x;
  const int lane = tid & 63, wv = tid >> 6;
  const int i0 = blockIdx.x * SCAN_CHUNK + tid * 8;
  int sacc[8];
  int run = 0;
#pragma unroll
  for (int k = 0; k < 8; k++) {
    const int v = (i0 + k < n) ? cnt[i0 + k] : 0;
    run += v;
    sacc[k] = run;
  }
  int x = run;
#pragma unroll
  for (int off = 1; off < 64; off <<= 1) {
    const int y = __shfl_up(x, off);
    if (lane >= off) x += y;
  }
  if (lane == 63) wtot[wv] = x;
  __syncthreads();
  int woff = 0;
#pragma unroll
  for (int k = 0; k < 4; k++) woff += (k < wv) ? wtot[k] : 0;
  const int excl = (x - run) + woff;
#pragma unroll
  for (int k = 0; k < 8; k++)
    if (i0 + k < n) row[i0 + k + 1] = excl + sacc[k];
  if (tid == 255) bsum[blockIdx.x] = excl + run;
}

__global__ __launch_bounds__(256) void scan3_kernel(
    const int* __restrict__ bsum, int* __restrict__ row, int n) {
  __shared__ int off_s;
  const int b = blockIdx.x;
  const int tid = threadIdx.x;
  if (tid < 64) {
    int v = (tid < b) ? bsum[tid] : 0;
#pragma unroll
    for (int off = 32; off; off >>= 1) v += __shfl_xor(v, off);
    if (tid == 0) off_s = v;
  }
  __syncthreads();
  const int off = off_s;
  if (b == 0) {
    if (tid == 0) row[0] = 0;
    return;
  }
  const int i0 = b * SCAN_CHUNK + tid * 8;
#pragma unroll
  for (int k = 0; k < 8; k++)
    if (i0 + k < n) row[i0 + k + 1] += off;
}

__global__ __launch_bounds__(T_CSR) void scatter2_kernel(
    const int* __restrict__ src, const int* __restrict__ dst,
    const unsigned short* __restrict__ PH, const int* __restrict__ rowU,
    const int* __restrict__ rowI, int* __restrict__ adjU,
    int* __restrict__ adjI) {
  __shared__ int pos[HSLOTS];
  const int p = blockIdx.x & (P_PART - 1);
  const int s = blockIdx.x >> 3;
  const int uLo = p * U_LOC, iLo = p * I_LOC;
  const unsigned short* pre = PH + (size_t)blockIdx.x * HSLOTS;
  for (int i = threadIdx.x; i < U_LOC; i += T_CSR)
    pos[i] = rowU[uLo + i] + (int)__builtin_nontemporal_load(&pre[i]);
  for (int i = threadIdx.x; i < I_LOC; i += T_CSR)
    pos[U_LOC + i] = rowI[iLo + i] + (int)__builtin_nontemporal_load(&pre[U_LOC + i]);
  __syncthreads();
  const int e0 = s * E_SLICE;
  const i32x4* s4 = reinterpret_cast<const i32x4*>(src + e0);
  const i32x4* d4 = reinterpret_cast<const i32x4*>(dst + e0);
  for (int i = threadIdx.x; i < Q_SLICE; i += T_CSR) {
    const i32x4 us = s4[i];
    const i32x4 ds = d4[i];
#pragma unroll
    for (int q = 0; q < 4; q++) {
      const int u = us[q], it = ds[q];
      const int ul = u - uLo, il = it - iLo;
      if ((unsigned)ul < (unsigned)U_LOC) {
        const int pp = atomicAdd(&pos[ul], 1);
        adjU[pp] = it;
      }
      if ((unsigned)il < (unsigned)I_LOC) {
        const int pp = atomicAdd(&pos[U_LOC + il], 1);
        adjI[pp] = u;
      }
    }
  }
}

// ---------------- aggregations: 4 neighbor rows per wave instruction ----------
__global__ __launch_bounds__(256) void agg_max_kernel(
    const unsigned short* __restrict__ feat, const int* __restrict__ rowptr,
    const int* __restrict__ adj, unsigned short* __restrict__ out, int nseg) {
  const int lane = threadIdx.x & 63;
  const int wid  = rfl((int)(threadIdx.x >> 6));
  const int g    = lane >> 4;
  const int c4   = (lane & 15) * 4;
  for (int s = blockIdx.x * 4 + wid; s < nseg; s += gridDim.x * 4) {
    const int beg = rowptr[s], end = rowptr[s + 1];
    float m0 = -INFINITY, m1 = -INFINITY, m2 = -INFINITY, m3 = -INFINITY;
    float n0 = -INFINITY, n1 = -INFINITY, n2 = -INFINITY, n3 = -INFINITY;
    int j = beg;
    for (; j + 8 <= end; j += 8) {
      const int ia = adj[j + g];
      const int ib = adj[j + 4 + g];
      const uint2 va = *reinterpret_cast<const uint2*>(feat + (size_t)ia * H + c4);
      const uint2 vb = *reinterpret_cast<const uint2*>(feat + (size_t)ib * H + c4);
      m0 = fmaxf(m0, bfu_lo(va.x)); m1 = fmaxf(m1, bfu_hi(va.x));
      m2 = fmaxf(m2, bfu_lo(va.y)); m3 = fmaxf(m3, bfu_hi(va.y));
      n0 = fmaxf(n0, bfu_lo(vb.x)); n1 = fmaxf(n1, bfu_hi(vb.x));
      n2 = fmaxf(n2, bfu_lo(vb.y)); n3 = fmaxf(n3, bfu_hi(vb.y));
    }
    for (; j < end; j += 4) {
      if (j + g < end) {
        const int ia = adj[j + g];
        const uint2 va = *reinterpret_cast<const uint2*>(feat + (size_t)ia * H + c4);
        m0 = fmaxf(m0, bfu_lo(va.x)); m1 = fmaxf(m1, bfu_hi(va.x));
        m2 = fmaxf(m2, bfu_lo(va.y)); m3 = fmaxf(m3, bfu_hi(va.y));
      }
    }
    m0 = fmaxf(m0, n0); m1 = fmaxf(m1, n1);
    m2 = fmaxf(m2, n2); m3 = fmaxf(m3, n3);
    m0 = fmaxf(m0, __shfl_xor(m0, 16)); m0 = fmaxf(m0, __shfl_xor(m0, 32));
    m1 = fmaxf(m1, __shfl_xor(m1, 16)); m1 = fmaxf(m1, __shfl_xor(m1, 32));
    m2 = fmaxf(m2, __shfl_xor(m2, 16)); m2 = fmaxf(m2, __shfl_xor(m2, 32));
    m3 = fmaxf(m3, __shfl_xor(m3, 16)); m3 = fmaxf(m3, __shfl_xor(m3, 32));
    if (lane < 16) {
      uint2 o;
      if (end > beg) {
        o.x = (unsigned)f2bf(m0) | ((unsigned)f2bf(m1) << 16);
        o.y = (unsigned)f2bf(m2) | ((unsigned)f2bf(m3) << 16);
      } else {
        o.x = 0; o.y = 0;   // empty segment -> 0 (PyG)
      }
      *reinterpret_cast<uint2*>(out + (size_t)s * H + c4) = o;
    }
  }
}

__global__ __launch_bounds__(256) void agg_mean_kernel(
    const unsigned short* __restrict__ feat, const int* __restrict__ rowptr,
    const int* __restrict__ adj, unsigned short* __restrict__ out, int nseg) {
  const int lane = threadIdx.x & 63;
  const int wid  = rfl((int)(threadIdx.x >> 6));
  const int g    = lane >> 4;
  const int c4   = (lane & 15) * 4;
  for (int s = blockIdx.x * 4 + wid; s < nseg; s += gridDim.x * 4) {
    const int beg = rowptr[s], end = rowptr[s + 1];
    float a0 = 0.f, a1 = 0.f, a2 = 0.f, a3 = 0.f;
    float b0 = 0.f, b1 = 0.f, b2 = 0.f, b3 = 0.f;
    int j = beg;
    for (; j + 8 <= end; j += 8) {
      const int ia = adj[j + g];
      const int ib = adj[j + 4 + g];
      const uint2 va = *reinterpret_cast<const uint2*>(feat + (size_t)ia * H + c4);
      const uint2 vb = *reinterpret_cast<const uint2*>(feat + (size_t)ib * H + c4);
      a0 += bfu_lo(va.x); a1 += bfu_hi(va.x);
      a2 += bfu_lo(va.y); a3 += bfu_hi(va.y);
      b0 += bfu_lo(vb.x); b1 += bfu_hi(vb.x);
      b2 += bfu_lo(vb.y); b3 += bfu_hi(vb.y);
    }
    for (; j < end; j += 4) {
      if (j + g < end) {
        const int ia = adj[j + g];
        const uint2 va = *reinterpret_cast<const uint2*>(feat + (size_t)ia * H + c4);
        a0 += bfu_lo(va.x); a1 += bfu_hi(va.x);
        a2 += bfu_lo(va.y); a3 += bfu_hi(va.y);
      }
    }
    a0 += b0; a1 += b1; a2 += b2; a3 += b3;
    a0 += __shfl_xor(a0, 16); a0 += __shfl_xor(a0, 32);
    a1 += __shfl_xor(a1, 16); a1 += __shfl_xor(a1, 32);
    a2 += __shfl_xor(a2, 16); a2 += __shfl_xor(a2, 32);
    a3 += __shfl_xor(a3, 16); a3 += __shfl_xor(a3, 32);
    if (lane < 16) {
      const float inv = 1.f / (float)((end - beg) > 1 ? (end - beg) : 1);
      uint2 o;
      o.x = (unsigned)f2bf(a0 * inv) | ((unsigned)f2bf(a1 * inv) << 16);
      o.y = (unsigned)f2bf(a2 * inv) | ((unsigned)f2bf(a3 * inv) << 16);
      *reinterpret_cast<uint2*>(out + (size_t)s * H + c4) = o;
    }
  }
}

// ---------------- head via MFMA: 16 edges/wave ----------------
__global__ __launch_bounds__(256) void head_mfma(
    const unsigned short* __restrict__ ux, const unsigned short* __restrict__ ix,
    const int* __restrict__ eliU, const int* __restrict__ eliI,
    const unsigned short* __restrict__ W1f, const float* __restrict__ b1,
    const float* __restrict__ W2, const float* __restrict__ b2,
    float* __restrict__ out) {
  const int lane = threadIdx.x & 63;
  const int wave = rfl((int)(threadIdx.x >> 6));
  const int r0 = (blockIdx.x * 4 + wave) * 16;
  if (r0 >= NB) return;
  const int rr = r0 + (lane & 15);
  const int rc = rr < NB ? rr : NB - 1;
  const int idxU = eliU[rc], idxI = eliI[rc];
  const int k0 = (lane >> 4) * 8;
  f32x4 acc[4] = {};
#pragma unroll
  for (int ks = 0; ks < 4; ks++) {
    const unsigned short* ap = (ks < 2)
        ? ux + (size_t)idxU * 64 + (ks & 1) * 32 + k0
        : ix + (size_t)idxI * 64 + (ks & 1) * 32 + k0;
    const bf16x8 af = *reinterpret_cast<const bf16x8*>(ap);
#pragma unroll
    for (int ct = 0; ct < 4; ct++) {
      const bf16x8 bfr = *reinterpret_cast<const bf16x8*>(
          W1f + ((size_t)(ks * 4 + ct) * 64 + lane) * 8);
      acc[ct] = __builtin_amdgcn_mfma_f32_16x16x32_bf16(af, bfr, acc[ct], 0, 0, 0);
    }
  }
  float p[4][4];
#pragma unroll
  for (int i = 0; i < 4; i++)
#pragma unroll
    for (int o = 0; o < 4; o++) p[i][o] = 0.f;
#pragma unroll
  for (int ct = 0; ct < 4; ct++) {
    const int col = ct * 16 + (lane & 15);
    const float bb = b1[col];
    const float wa = W2[col * 4 + 0], wb = W2[col * 4 + 1];
    const float wc = W2[col * 4 + 2], wd = W2[col * 4 + 3];
#pragma unroll
    for (int i = 0; i < 4; i++) {
      const float h = fmaxf(acc[ct][i] + bb, 0.f);
      p[i][0] = fmaf(h, wa, p[i][0]);
      p[i][1] = fmaf(h, wb, p[i][1]);
      p[i][2] = fmaf(h, wc, p[i][2]);
      p[i][3] = fmaf(h, wd, p[i][3]);
    }
  }
#pragma unroll
  for (int off = 1; off < 16; off <<= 1) {
#pragma unroll
    for (int i = 0; i < 4; i++) {
      p[i][0] += __shfl_xor(p[i][0], off);
      p[i][1] += __shfl_xor(p[i][1], off);
      p[i][2] += __shfl_xor(p[i][2], off);
      p[i][3] += __shfl_xor(p[i][3], off);
    }
  }
  if ((lane & 15) == 0) {
    const int row0 = r0 + (lane >> 4) * 4;
#pragma unroll
    for (int i = 0; i < 4; i++) {
      const int r = row0 + i;
      if (r < NB) {
        float4 o4 = { p[i][0] + b2[0], p[i][1] + b2[1],
                      p[i][2] + b2[2], p[i][3] + b2[3] };
        *reinterpret_cast<float4*>(out + (size_t)r * 4) = o4;
      }
    }
  }
}

// ---------------- launch ----------------
extern "C" void kernel_launch(void* const* d_in, const int* in_sizes, int n_in,
                              void* d_out, int out_size, void* d_ws, size_t ws_size,
                              hipStream_t stream) {
  const float* userF = (const float*)d_in[0];
  const float* itemF = (const float*)d_in[1];
  const int*   src   = (const int*)d_in[2];
  const int*   dst   = src + NE;
  const int*   eliU  = (const int*)d_in[3];
  const int*   eliI  = eliU + NB;
  const float* upW = (const float*)d_in[4],  *upb = (const float*)d_in[5];
  const float* ipW = (const float*)d_in[6],  *ipb = (const float*)d_in[7];
  const float* ulW = (const float*)d_in[8],  *ulb = (const float*)d_in[9];
  const float* urW = (const float*)d_in[10];
  const float* ilW = (const float*)d_in[11], *ilb = (const float*)d_in[12];
  const float* irW = (const float*)d_in[13];
  const float* ug  = (const float*)d_in[14], *ube = (const float*)d_in[15];
  const float* um  = (const float*)d_in[16], *uv  = (const float*)d_in[17];
  const float* ig  = (const float*)d_in[18], *ibe = (const float*)d_in[19];
  const float* im  = (const float*)d_in[20], *iv  = (const float*)d_in[21];
  const float* f1W = (const float*)d_in[22], *f1b = (const float*)d_in[23];
  const float* f2W = (const float*)d_in[24], *f2b = (const float*)d_in[25];
  float* outp = (float*)d_out;

  char* p = (char*)d_ws;
  auto alloc = [&](size_t bytes) {
    char* r = p;
    p += (bytes + 255) & ~(size_t)255;
    return r;
  };
  unsigned short* ux0 = (unsigned short*)alloc((size_t)N_USERS * H * 2);
  unsigned short* ix0 = (unsigned short*)alloc((size_t)N_ITEMS * H * 2);
  char* grp = alloc((size_t)38400 * 1024);
  unsigned short* agU = (unsigned short*)grp;
  unsigned short* agI = agU + (size_t)N_USERS * H;
  unsigned short* ux1 = agI + (size_t)N_ITEMS * H;
  unsigned short* ix1 = ux1 + (size_t)N_USERS * H;
  unsigned short* PH = (unsigned short*)grp;  // 400 x 18750 u16 = 15 MB
  int*   rowU = (int*)alloc((size_t)(N_USERS + 1) * 4);
  int*   rowI = (int*)alloc((size_t)(N_ITEMS + 1) * 4);
  int*   cntU = (int*)alloc((size_t)N_USERS * 4);
  int*   cntI = (int*)alloc((size_t)N_ITEMS * 4);
  int*   adjU = (int*)alloc((size_t)NE * 4);
  int*   adjI = (int*)alloc((size_t)NE * 4);
  int*   bsumU = (int*)alloc(64 * 4);
  int*   bsumI = (int*)alloc(64 * 4);
  unsigned short* wpack = (unsigned short*)alloc((size_t)32 * 2048 * 2);  // 256 KB

  const int G = 2048, T = 256;
  const int SBU = (N_USERS + SCAN_CHUNK - 1) / SCAN_CHUNK;  // 49
  const int SBI = (N_ITEMS + SCAN_CHUNK - 1) / SCAN_CHUNK;  // 25
  pack_kernel<<<32, T, 0, stream>>>(upW, ipW, ulW, urW, ilW, irW, f1W, wpack);
  fused_hist_proj<<<NBLK_CSR + GU_BLK + GI_BLK, T_CSR, 0, stream>>>(
      src, dst, PH, userF, itemF, wpack, upb, ipb, ux0, ix0);
  combine_kernel<<<(P_PART * HSLOTS + 255) / 256, T, 0, stream>>>(PH, cntU, cntI);
  scan1_kernel<<<SBU, T, 0, stream>>>(cntU, rowU, bsumU, N_USERS);
  scan1_kernel<<<SBI, T, 0, stream>>>(cntI, rowI, bsumI, N_ITEMS);
  scan3_kernel<<<SBU, T, 0, stream>>>(bsumU, rowU, N_USERS);
  scan3_kernel<<<SBI, T, 0, stream>>>(bsumI, rowI, N_ITEMS);
  scatter2_kernel<<<NBLK_CSR, T_CSR, 0, stream>>>(src, dst, PH, rowU, rowI, adjU, adjI);

  const unsigned short* uin = ux0;
  const unsigned short* iin = ix0;
  unsigned short* uout = ux1;
  unsigned short* iout = ix1;
  const int GU = (N_USERS + 63) / 64, GI = (N_ITEMS + 63) / 64;
  for (int l = 0; l < 2; l++) {
    unsigned short* cwU = wpack + (12 + 4 * (0 + l)) * 2048;
    unsigned short* cwI = wpack + (12 + 4 * (2 + l)) * 2048;
    agg_max_kernel<<<G, T, 0, stream>>>(iin, rowU, adjU, agU, N_USERS);
    conv_mfma<<<GU, T, 0, stream>>>(agU, uin, cwU, ulb + l * 64,
                                    ug + l * 64, ube + l * 64,
                                    um + l * 64, uv + l * 64, uout, N_USERS);
    agg_mean_kernel<<<G, T, 0, stream>>>(uin, rowI, adjI, agI, N_ITEMS);
    conv_mfma<<<GI, T, 0, stream>>>(agI, iin, cwI, ilb + l * 64,
                                    ig + l * 64, ibe + l * 64,
                                    im + l * 64, iv + l * 64, iout, N_ITEMS);
    const unsigned short* t;
    t = uin; uin = uout; uout = (unsigned short*)t;
    t = iin; iin = iout; iout = (unsigned short*)t;
  }
  head_mfma<<<(NB / 16 + 3) / 4, T, 0, stream>>>(uin, iin, eliU, eliI,
                                                 wpack + 28 * 2048, f1b, f2W, f2b, outp);
}